// Round 1
// 145.831 us; speedup vs baseline: 1.0162x; 1.0162x over previous
//
#include <hip/hip_runtime.h>
#include <stdint.h>

#define BB 16
#define NN 2048
#define CC 80
#define CONF_THRV 0.5f
#define NMS_THRV 0.5f

// ============ K1: ballot-compacted dense keys + packed rank scan ===========
// Grid (32, BB), 64-thread (1-wave) blocks. Each block rebuilds the batch's
// VALID keys into a dense LDS array in ascending-anchor order via ballot
// prefix compaction (deterministic — identical in every block). Since every
// invalid key (flip(-inf)) is strictly below every valid key, rank over the
// dense array equals rank over the full array: rank_i = #{valid j: key_j >
// key_i}. Lanes are fully packed (slot s<nv <=> lane scans) and the scan is
// nv (~1024) keys instead of NN=2048, spread over ~256 active one-wave
// blocks instead of 128 half-valid 4-wave blocks => ~8x less LDS-broadcast
// time per CU than the previous per-anchor scan.
__global__ __launch_bounds__(64) void k_rank_all(
    const float4* __restrict__ boxes,
    const float* __restrict__ obj,
    const float* __restrict__ logits,
    float4* __restrict__ sxyxy,
    float* __restrict__ sarea,
    float* __restrict__ sobj,
    float* __restrict__ sconf,
    int* __restrict__ scls,
    int* __restrict__ nvalid) {
  __shared__ unsigned long long lk[NN + 4];   // dense keys + zero pad (16.4 KB)
  int b = blockIdx.y;
  int t = threadIdx.x;
  size_t base = (size_t)b * NN;
  unsigned long long mlt = (1ull << t) - 1ull;  // lanemask_lt

  // Single staging pass: count + compact. `run` is wave-uniform (same ballot
  // in all lanes), dense slot = run + popc(ballot & lanemask_lt) is the
  // ascending-anchor prefix => deterministic across blocks.
  int run = 0;
  #pragma unroll 8
  for (int r = 0; r < NN / 64; ++r) {
    int a = r * 64 + t;
    float o = obj[base + a];
    bool v = o > CONF_THRV;
    unsigned long long m = __ballot(v);
    if (v) {
      // valid => o > 0 => sign bit clear; descending-order flip is just |MSB.
      unsigned u = __float_as_uint(o) | 0x80000000u;
      lk[run + __popcll(m & mlt)] =
          ((unsigned long long)u << 32) |
          (unsigned long long)(0xFFFFFFFFu - (unsigned)a);
    }
    run += __popcll(m);
  }
  int nv = run;
  if (t < 4) lk[nv + t] = 0ull;               // zero pad: 0 > ki never counts
  if (blockIdx.x == 0 && t == 0) nvalid[b] = nv;
  __syncthreads();

  int s = blockIdx.x * 64 + t;                // dense slot owned by this lane
  if (s >= nv) return;                        // fully-packed: no idle lanes
  unsigned long long ki = lk[s];

  int rank = 0;
  int nvr = (nv + 3) & ~3;                    // round to 4-key scan width
  const ulonglong2* lk2 = (const ulonglong2*)lk;
  #pragma unroll 4
  for (int j = 0; j < nvr / 2; j += 2) {      // broadcast LDS reads, b128 pairs
    ulonglong2 a2 = lk2[j];
    ulonglong2 c2 = lk2[j + 1];
    rank += (a2.x > ki) + (a2.y > ki) + (c2.x > ki) + (c2.y > ki);
  }

  // recover original anchor index + exact obj bits from the key itself
  int i = (int)(0xFFFFFFFFu - (unsigned)(ki & 0xFFFFFFFFull));
  float oi = __uint_as_float((unsigned)(ki >> 32) & 0x7FFFFFFFu);

  // class argmax for own (valid) anchor only — ~half the logits traffic
  const float4* lp = (const float4*)(logits + (base + i) * CC);
  float best = -INFINITY;
  int bi = 0;
  #pragma unroll
  for (int q = 0; q < CC / 4; ++q) {
    float4 v4 = lp[q];
    if (v4.x > best) { best = v4.x; bi = 4 * q + 0; }
    if (v4.y > best) { best = v4.y; bi = 4 * q + 1; }
    if (v4.z > best) { best = v4.z; bi = 4 * q + 2; }
    if (v4.w > best) { best = v4.w; bi = 4 * q + 3; }
  }

  float4 bx = boxes[base + i];
  float hw = bx.z / 2.0f, hh = bx.w / 2.0f;
  float x1 = bx.x - hw, y1 = bx.y - hh;
  float x2 = bx.x + hw, y2 = bx.y + hh;
  sxyxy[base + rank] = make_float4(x1, y1, x2, y2);
  sarea[base + rank] = __fmul_rn(x2 - x1 + 1.0f, y2 - y1 + 1.0f);
  sobj[base + rank] = oi;
  sconf[base + rank] = best;
  scls[base + rank] = bi;
}

// ============ K2: suppression masks, transposed, only live words ===========
// masksT[(b*64 + w)*NN + i] = bits for rows j in [32w,32w+32) suppressed by i.
// Only words w < nwords=ceil(nv/32) are stored (i in [0,2048) all written,
// zeros where dead, so the scan's rounded-up chunks OR in zeros harmlessly).
__global__ void k_masks(const float4* __restrict__ sxyxy,
                        const float* __restrict__ sarea,
                        const int* __restrict__ scls,
                        const int* __restrict__ nvalid,
                        uint32_t* __restrict__ masksT) {
  int b = blockIdx.y;
  int pair = blockIdx.x * blockDim.x + threadIdx.x;  // [0, NN*64)
  int i = pair & (NN - 1);
  int w = pair >> 11;
  int nv = nvalid[b];
  int nwords = (nv + 31) >> 5;
  if (w >= nwords) return;              // scan never reads these words
  size_t base = (size_t)b * NN;
  uint32_t bits = 0;
  int j0 = w * 32;
  int jend = min(j0 + 32, nv);
  int jstart = max(j0, i + 1);
  if (i < nv && jstart < jend) {
    float4 bi = sxyxy[base + i];
    float ai = sarea[base + i];
    int ci = scls[base + i];
    for (int j = jstart; j < jend; ++j) {
      float4 bj = sxyxy[base + j];
      float xx1 = fmaxf(bi.x, bj.x);
      float yy1 = fmaxf(bi.y, bj.y);
      float xx2 = fminf(bi.z, bj.z);
      float yy2 = fminf(bi.w, bj.w);
      float cw = fmaxf(xx2 - xx1 + 1.0f, 0.0f);
      float ch = fmaxf(yy2 - yy1 + 1.0f, 0.0f);
      float inter = __fmul_rn(cw, ch);               // block fp-contract
      float aj = sarea[base + j];
      float denom = (ai + aj) - inter;               // same assoc as reference
      float iou = inter / denom;
      if (iou >= NMS_THRV && scls[base + j] == ci) bits |= (1u << (j - j0));
    }
  }
  masksT[((size_t)b * 64 + w) * NN + i] = bits;
}

// ============ K3: chunked greedy scan (wave 0) + output write ==============
// Dynamic chunk count nch4 = ceil(nch/4)*4; lanes >= nwords are
// load-predicated to zero (their words were never stored). Static named
// buffers only — round-3 lesson: dynamic register indexing => scratch.
__global__ __launch_bounds__(512) void k_scan_write(
    const uint32_t* __restrict__ masksT,
    const int* __restrict__ nvalid,
    const float4* __restrict__ sxyxy,
    const float* __restrict__ sobj,
    const float* __restrict__ sconf,
    const int* __restrict__ scls,
    float* __restrict__ out) {
  __shared__ uint32_t rsh[64];
  int b = blockIdx.x;
  int t = threadIdx.x;
  int nv = nvalid[b];

  if (t < 64) {
    int lane = t;
    int nwords = (nv + 31) >> 5;
    int nch4 = (nwords + 3) & ~3;       // chunks, rounded to pipeline depth
    bool act = lane < nwords;
    const uint4* col = (const uint4*)(masksT + ((size_t)b * 64 + lane) * NN);
    uint32_t remv = 0;
    uint4 z4; z4.x = z4.y = z4.z = z4.w = 0u;
    uint4 A[8], B[8], C[8], D[8];
    #pragma unroll
    for (int q = 0; q < 8; ++q) { A[q] = z4; B[q] = z4; C[q] = z4; D[q] = z4; }
#define LOADBUF(BUF, CH) do {                                          \
      if (act) {                                                       \
        int rr = (CH) < 64 ? (CH) : 0;                                 \
        _Pragma("unroll")                                              \
        for (int q = 0; q < 8; ++q) BUF[q] = col[rr * 8 + q];          \
      }                                                                \
    } while (0)
    LOADBUF(A, 0); LOADBUF(B, 1); LOADBUF(C, 2); LOADBUF(D, 3);
#define STEP(BUF, CH, RCH) do {                                        \
      uint32_t cur[32];                                                \
      _Pragma("unroll")                                                \
      for (int q = 0; q < 8; ++q) {                                    \
        cur[4*q+0] = BUF[q].x; cur[4*q+1] = BUF[q].y;                  \
        cur[4*q+2] = BUF[q].z; cur[4*q+3] = BUF[q].w;                  \
      }                                                                \
      LOADBUF(BUF, RCH);                                               \
      uint32_t all_or = 0;                                             \
      _Pragma("unroll")                                                \
      for (int d = 0; d < 32; ++d) all_or |= cur[d];                   \
      uint32_t word_c = (uint32_t)__shfl((int)remv, (CH), 64);         \
      uint32_t diag   = (uint32_t)__shfl((int)all_or, (CH), 64);       \
      if (diag == 0u) {                                                \
        if (word_c == 0u) {                                            \
          remv |= all_or;                                              \
        } else {                                                       \
          uint32_t acc = 0;                                            \
          _Pragma("unroll")                                            \
          for (int d = 0; d < 32; ++d)                                 \
            acc |= ((word_c >> d) & 1u) ? 0u : cur[d];                 \
          remv |= acc;                                                 \
        }                                                              \
      } else {                                                         \
        uint32_t wc = word_c, acc = 0;                                 \
        _Pragma("unroll")                                              \
        for (int d = 0; d < 32; ++d) {                                 \
          uint32_t dd = (uint32_t)__shfl((int)cur[d], (CH), 64);       \
          if (((wc >> d) & 1u) == 0u) { wc |= dd; acc |= cur[d]; }     \
        }                                                              \
        remv |= acc;                                                   \
      }                                                                \
    } while (0)
    for (int c = 0; c < nch4; c += 4) {
      STEP(A, c + 0, c + 4);
      STEP(B, c + 1, c + 5);
      STEP(C, c + 2, c + 6);
      STEP(D, c + 3, c + 7);
    }
#undef STEP
#undef LOADBUF
    rsh[lane] = remv;
  }
  __syncthreads();

  #pragma unroll
  for (int rep = 0; rep < 4; ++rep) {
    int r = t + rep * 512;
    size_t idx = (size_t)b * NN + r;
    bool keep = false;
    if (r < nv) {
      uint32_t wrd = rsh[r >> 5];
      keep = !((wrd >> (r & 31)) & 1u);
    }
    float4 xy = make_float4(0.f, 0.f, 0.f, 0.f);
    float o = 0.f, cf = 0.f, cl = 0.f;
    if (keep) {
      xy = sxyxy[idx];
      o = sobj[idx];
      cf = sconf[idx];
      cl = (float)scls[idx];
    }
    float4* op = (float4*)(out + idx * 8);
    op[0] = make_float4((float)b, xy.x, xy.y, xy.z);
    op[1] = make_float4(xy.w, o, cf, cl);
  }
}

extern "C" void kernel_launch(void* const* d_in, const int* in_sizes, int n_in,
                              void* d_out, int out_size, void* d_ws, size_t ws_size,
                              hipStream_t stream) {
  const float4* boxes = (const float4*)d_in[0];        // [B][N][4]
  const float* obj = (const float*)d_in[1];            // [B][N]
  const float* logits = (const float*)d_in[2];         // [B][N][80]
  float* out = (float*)d_out;                          // [B][N][8]

  char* ws = (char*)d_ws;
  size_t off = 0;
  float4* sxyxy = (float4*)(ws + off);            off += (size_t)BB * NN * 16;
  float* sarea = (float*)(ws + off);              off += (size_t)BB * NN * 4;
  float* sobj = (float*)(ws + off);               off += (size_t)BB * NN * 4;
  float* sconf = (float*)(ws + off);              off += (size_t)BB * NN * 4;
  int* scls = (int*)(ws + off);                   off += (size_t)BB * NN * 4;
  int* nvalid = (int*)(ws + off);                 off += 256;
  uint32_t* masksT = (uint32_t*)(ws + off);       off += (size_t)BB * NN * 64 * 4;

  hipLaunchKernelGGL(k_rank_all, dim3(32, BB), dim3(64), 0, stream,
                     boxes, obj, logits,
                     sxyxy, sarea, sobj, sconf, scls, nvalid);
  hipLaunchKernelGGL(k_masks, dim3(NN * 64 / 256, BB), dim3(256), 0, stream,
                     sxyxy, sarea, scls, nvalid, masksT);
  hipLaunchKernelGGL(k_scan_write, dim3(BB), dim3(512), 0, stream,
                     masksT, nvalid, sxyxy, sobj, sconf, scls, out);
}

// Round 2
// 140.169 us; speedup vs baseline: 1.0573x; 1.0404x over previous
//
#include <hip/hip_runtime.h>
#include <stdint.h>

#define BB 16
#define NN 2048
#define CC 80
#define CONF_THRV 0.5f
#define NMS_THRV 0.5f

// ============ K1: ballot-compacted dense keys + packed rank scan ===========
// Grid (32, BB), 64-thread (1-wave) blocks. Each block rebuilds the batch's
// VALID keys into a dense LDS array in ascending-anchor order via ballot
// prefix compaction (deterministic — identical in every block). Since every
// invalid key (flip(-inf)) is strictly below every valid key, rank over the
// dense array equals rank over the full array: rank_i = #{valid j: key_j >
// key_i}. Lanes are fully packed (slot s<nv <=> lane scans).
__global__ __launch_bounds__(64) void k_rank_all(
    const float4* __restrict__ boxes,
    const float* __restrict__ obj,
    const float* __restrict__ logits,
    float4* __restrict__ sxyxy,
    float* __restrict__ sarea,
    float* __restrict__ sobj,
    float* __restrict__ sconf,
    int* __restrict__ scls,
    int* __restrict__ nvalid) {
  __shared__ unsigned long long lk[NN + 4];   // dense keys + zero pad (16.4 KB)
  int b = blockIdx.y;
  int t = threadIdx.x;
  size_t base = (size_t)b * NN;
  unsigned long long mlt = (1ull << t) - 1ull;  // lanemask_lt

  // Single staging pass: count + compact. `run` is wave-uniform (same ballot
  // in all lanes), dense slot = run + popc(ballot & lanemask_lt) is the
  // ascending-anchor prefix => deterministic across blocks.
  int run = 0;
  #pragma unroll 8
  for (int r = 0; r < NN / 64; ++r) {
    int a = r * 64 + t;
    float o = obj[base + a];
    bool v = o > CONF_THRV;
    unsigned long long m = __ballot(v);
    if (v) {
      // valid => o > 0 => sign bit clear; descending-order flip is just |MSB.
      unsigned u = __float_as_uint(o) | 0x80000000u;
      lk[run + __popcll(m & mlt)] =
          ((unsigned long long)u << 32) |
          (unsigned long long)(0xFFFFFFFFu - (unsigned)a);
    }
    run += __popcll(m);
  }
  int nv = run;
  if (t < 4) lk[nv + t] = 0ull;               // zero pad: 0 > ki never counts
  if (blockIdx.x == 0 && t == 0) nvalid[b] = nv;
  __syncthreads();

  int s = blockIdx.x * 64 + t;                // dense slot owned by this lane
  if (s >= nv) return;                        // fully-packed: no idle lanes
  unsigned long long ki = lk[s];

  int rank = 0;
  int nvr = (nv + 3) & ~3;                    // round to 4-key scan width
  const ulonglong2* lk2 = (const ulonglong2*)lk;
  #pragma unroll 4
  for (int j = 0; j < nvr / 2; j += 2) {      // broadcast LDS reads, b128 pairs
    ulonglong2 a2 = lk2[j];
    ulonglong2 c2 = lk2[j + 1];
    rank += (a2.x > ki) + (a2.y > ki) + (c2.x > ki) + (c2.y > ki);
  }

  // recover original anchor index + exact obj bits from the key itself
  int i = (int)(0xFFFFFFFFu - (unsigned)(ki & 0xFFFFFFFFull));
  float oi = __uint_as_float((unsigned)(ki >> 32) & 0x7FFFFFFFu);

  // class argmax for own (valid) anchor only — ~half the logits traffic
  const float4* lp = (const float4*)(logits + (base + i) * CC);
  float best = -INFINITY;
  int bi = 0;
  #pragma unroll
  for (int q = 0; q < CC / 4; ++q) {
    float4 v4 = lp[q];
    if (v4.x > best) { best = v4.x; bi = 4 * q + 0; }
    if (v4.y > best) { best = v4.y; bi = 4 * q + 1; }
    if (v4.z > best) { best = v4.z; bi = 4 * q + 2; }
    if (v4.w > best) { best = v4.w; bi = 4 * q + 3; }
  }

  float4 bx = boxes[base + i];
  float hw = bx.z / 2.0f, hh = bx.w / 2.0f;
  float x1 = bx.x - hw, y1 = bx.y - hh;
  float x2 = bx.x + hw, y2 = bx.y + hh;
  sxyxy[base + rank] = make_float4(x1, y1, x2, y2);
  sarea[base + rank] = __fmul_rn(x2 - x1 + 1.0f, y2 - y1 + 1.0f);
  sobj[base + rank] = oi;
  sconf[base + rank] = best;
  scls[base + rank] = bi;
}

// ============ K2: suppression masks, LDS-staged j-tile, unrolled ===========
// masksT[(b*64 + w)*NN + i] = bits for rows j in [32w,32w+32) suppressed by i.
// w = pair>>11 is BLOCK-uniform (256 | 2048), so the 32-row j-tile is staged
// once per block into 768 B of LDS; the inner loop is then a fully-unrolled
// 32-step predicated LDS-broadcast + VALU body with NO global loads — the
// previous dynamic-bound loop serialized ~32 dependent L2-latency loads per
// wave. Out-of-range jj reads hit uninitialized LDS but the in-range
// predicate is ANDed into the bit condition, so garbage can never set a bit.
// FP expressions are bit-identical to the previous version.
__global__ __launch_bounds__(256) void k_masks(
    const float4* __restrict__ sxyxy,
    const float* __restrict__ sarea,
    const int* __restrict__ scls,
    const int* __restrict__ nvalid,
    uint32_t* __restrict__ masksT) {
  int b = blockIdx.y;
  int t = threadIdx.x;
  int pair = blockIdx.x * 256 + t;       // [0, NN*64)
  int i = pair & (NN - 1);
  int w = pair >> 11;                    // block-uniform
  int nv = nvalid[b];
  int nwords = (nv + 31) >> 5;
  if (w >= nwords) return;               // block-uniform exit (scan skips these)
  size_t base = (size_t)b * NN;
  int j0 = w * 32;

  __shared__ float4 jbox[32];
  __shared__ float jarea[32];
  __shared__ int jcls[32];
  if (t < 32) {
    int j = j0 + t;
    if (j < nv) {
      jbox[t] = sxyxy[base + j];
      jarea[t] = sarea[base + j];
      jcls[t] = scls[base + j];
    }
  }
  __syncthreads();

  uint32_t bits = 0;
  if (i < nv) {
    int jend = min(j0 + 32, nv);
    int jstart = max(j0, i + 1);
    if (jstart < jend) {
      float4 bi = sxyxy[base + i];
      float ai = sarea[base + i];
      int ci = scls[base + i];
      #pragma unroll
      for (int jj = 0; jj < 32; ++jj) {
        int j = j0 + jj;
        bool inr = (j >= jstart) & (j < jend);
        float4 bj = jbox[jj];
        float xx1 = fmaxf(bi.x, bj.x);
        float yy1 = fmaxf(bi.y, bj.y);
        float xx2 = fminf(bi.z, bj.z);
        float yy2 = fminf(bi.w, bj.w);
        float cw = fmaxf(xx2 - xx1 + 1.0f, 0.0f);
        float ch = fmaxf(yy2 - yy1 + 1.0f, 0.0f);
        float inter = __fmul_rn(cw, ch);             // block fp-contract
        float aj = jarea[jj];
        float denom = (ai + aj) - inter;             // same assoc as reference
        float iou = inter / denom;
        if (inr && iou >= NMS_THRV && jcls[jj] == ci) bits |= (1u << jj);
      }
    }
  }
  masksT[((size_t)b * 64 + w) * NN + i] = bits;
}

// ============ K3: chunked greedy scan (wave 0) + output write ==============
// Dynamic chunk count nch4 = ceil(nch/4)*4; lanes >= nwords are
// load-predicated to zero (their words were never stored). Static named
// buffers only — round-3 lesson: dynamic register indexing => scratch.
__global__ __launch_bounds__(512) void k_scan_write(
    const uint32_t* __restrict__ masksT,
    const int* __restrict__ nvalid,
    const float4* __restrict__ sxyxy,
    const float* __restrict__ sobj,
    const float* __restrict__ sconf,
    const int* __restrict__ scls,
    float* __restrict__ out) {
  __shared__ uint32_t rsh[64];
  int b = blockIdx.x;
  int t = threadIdx.x;
  int nv = nvalid[b];

  if (t < 64) {
    int lane = t;
    int nwords = (nv + 31) >> 5;
    int nch4 = (nwords + 3) & ~3;       // chunks, rounded to pipeline depth
    bool act = lane < nwords;
    const uint4* col = (const uint4*)(masksT + ((size_t)b * 64 + lane) * NN);
    uint32_t remv = 0;
    uint4 z4; z4.x = z4.y = z4.z = z4.w = 0u;
    uint4 A[8], B[8], C[8], D[8];
    #pragma unroll
    for (int q = 0; q < 8; ++q) { A[q] = z4; B[q] = z4; C[q] = z4; D[q] = z4; }
#define LOADBUF(BUF, CH) do {                                          \
      if (act) {                                                       \
        int rr = (CH) < 64 ? (CH) : 0;                                 \
        _Pragma("unroll")                                              \
        for (int q = 0; q < 8; ++q) BUF[q] = col[rr * 8 + q];          \
      }                                                                \
    } while (0)
    LOADBUF(A, 0); LOADBUF(B, 1); LOADBUF(C, 2); LOADBUF(D, 3);
#define STEP(BUF, CH, RCH) do {                                        \
      uint32_t cur[32];                                                \
      _Pragma("unroll")                                                \
      for (int q = 0; q < 8; ++q) {                                    \
        cur[4*q+0] = BUF[q].x; cur[4*q+1] = BUF[q].y;                  \
        cur[4*q+2] = BUF[q].z; cur[4*q+3] = BUF[q].w;                  \
      }                                                                \
      LOADBUF(BUF, RCH);                                               \
      uint32_t all_or = 0;                                             \
      _Pragma("unroll")                                                \
      for (int d = 0; d < 32; ++d) all_or |= cur[d];                   \
      uint32_t word_c = (uint32_t)__shfl((int)remv, (CH), 64);         \
      uint32_t diag   = (uint32_t)__shfl((int)all_or, (CH), 64);       \
      if (diag == 0u) {                                                \
        if (word_c == 0u) {                                            \
          remv |= all_or;                                              \
        } else {                                                       \
          uint32_t acc = 0;                                            \
          _Pragma("unroll")                                            \
          for (int d = 0; d < 32; ++d)                                 \
            acc |= ((word_c >> d) & 1u) ? 0u : cur[d];                 \
          remv |= acc;                                                 \
        }                                                              \
      } else {                                                         \
        uint32_t wc = word_c, acc = 0;                                 \
        _Pragma("unroll")                                              \
        for (int d = 0; d < 32; ++d) {                                 \
          uint32_t dd = (uint32_t)__shfl((int)cur[d], (CH), 64);       \
          if (((wc >> d) & 1u) == 0u) { wc |= dd; acc |= cur[d]; }     \
        }                                                              \
        remv |= acc;                                                   \
      }                                                                \
    } while (0)
    for (int c = 0; c < nch4; c += 4) {
      STEP(A, c + 0, c + 4);
      STEP(B, c + 1, c + 5);
      STEP(C, c + 2, c + 6);
      STEP(D, c + 3, c + 7);
    }
#undef STEP
#undef LOADBUF
    rsh[lane] = remv;
  }
  __syncthreads();

  #pragma unroll
  for (int rep = 0; rep < 4; ++rep) {
    int r = t + rep * 512;
    size_t idx = (size_t)b * NN + r;
    bool keep = false;
    if (r < nv) {
      uint32_t wrd = rsh[r >> 5];
      keep = !((wrd >> (r & 31)) & 1u);
    }
    float4 xy = make_float4(0.f, 0.f, 0.f, 0.f);
    float o = 0.f, cf = 0.f, cl = 0.f;
    if (keep) {
      xy = sxyxy[idx];
      o = sobj[idx];
      cf = sconf[idx];
      cl = (float)scls[idx];
    }
    float4* op = (float4*)(out + idx * 8);
    op[0] = make_float4((float)b, xy.x, xy.y, xy.z);
    op[1] = make_float4(xy.w, o, cf, cl);
  }
}

extern "C" void kernel_launch(void* const* d_in, const int* in_sizes, int n_in,
                              void* d_out, int out_size, void* d_ws, size_t ws_size,
                              hipStream_t stream) {
  const float4* boxes = (const float4*)d_in[0];        // [B][N][4]
  const float* obj = (const float*)d_in[1];            // [B][N]
  const float* logits = (const float*)d_in[2];         // [B][N][80]
  float* out = (float*)d_out;                          // [B][N][8]

  char* ws = (char*)d_ws;
  size_t off = 0;
  float4* sxyxy = (float4*)(ws + off);            off += (size_t)BB * NN * 16;
  float* sarea = (float*)(ws + off);              off += (size_t)BB * NN * 4;
  float* sobj = (float*)(ws + off);               off += (size_t)BB * NN * 4;
  float* sconf = (float*)(ws + off);               off += (size_t)BB * NN * 4;
  int* scls = (int*)(ws + off);                   off += (size_t)BB * NN * 4;
  int* nvalid = (int*)(ws + off);                 off += 256;
  uint32_t* masksT = (uint32_t*)(ws + off);       off += (size_t)BB * NN * 64 * 4;

  hipLaunchKernelGGL(k_rank_all, dim3(32, BB), dim3(64), 0, stream,
                     boxes, obj, logits,
                     sxyxy, sarea, sobj, sconf, scls, nvalid);
  hipLaunchKernelGGL(k_masks, dim3(NN * 64 / 256, BB), dim3(256), 0, stream,
                     sxyxy, sarea, scls, nvalid, masksT);
  hipLaunchKernelGGL(k_scan_write, dim3(BB), dim3(512), 0, stream,
                     masksT, nvalid, sxyxy, sobj, sconf, scls, out);
}